// Round 2
// baseline (840.535 us; speedup 1.0000x reference)
//
#include <hip/hip_runtime.h>

// NNConv / MPNN, round 2: register-resident W2 panel, multi-tile blocks.
//   out-slice s owns o in [8s,8s+8); slice cols c = n*32 + i  (oo-major, i = lane).
//   Per block (512 thr, 8 waves): W2 slice panel in VGPRs (Bf[4][8] short8/lane,
//   loaded once), then loop ~24 edge tiles of 128 edges:
//     stage ef->Efs(bf16), H^T = W1T@Ef^T via MFMA (packed b64 writes to Hs),
//     K-loop: 8 ds_read_b128 + 32 MFMA per wave, NO barriers, acc init = b2;
//     contraction: x[e,i=lane]*acc, 32-lane DPP reduce (VALU), lanes31/63 atomicAdd.
//   3 barriers/tile. Atomics: exactly 6.4M (one per (e,o)).

#define E_TOTAL   200000
#define N_TILES   1563          // ceil(200000/128); last tile half-valid
#define OUT_BLKS  6250          // 1600000/256
#define W2K_BLKS  512           // 131072/256

typedef short short8 __attribute__((ext_vector_type(8)));
typedef short s16x4  __attribute__((ext_vector_type(4)));
typedef float f32x16 __attribute__((ext_vector_type(16)));

__device__ __forceinline__ short f2bf(float f) {
    union { float f; unsigned u; } cv; cv.f = f;
    unsigned r = cv.u + 0x7fffu + ((cv.u >> 16) & 1u);
    return (short)(r >> 16);
}

// f32 add of DPP-shifted value; bound_ctrl=1 -> 0 for invalid lanes
#define DPP_ADD(v, ctrl) \
    v += __int_as_float(__builtin_amdgcn_update_dpp(0, __float_as_int(v), ctrl, 0xF, 0xF, true))

// ---------------- setup: out = bias; W2 -> bf16 slice-major panel in ws ----------------
// W2k[s 4][c 256][k 128] bf16, c = n*32 + i, (i,o) = (col>>5, col&31), s = o>>3, n = o&7.
__global__ __launch_bounds__(256) void setup_kernel(const float* __restrict__ W2,
                                                    const float* __restrict__ bias,
                                                    float* __restrict__ out,
                                                    short* __restrict__ W2k) {
    int bid = blockIdx.x, tid = threadIdx.x;
    if (bid < OUT_BLKS) {
        int idx = bid * 256 + tid;
        out[idx] = bias[idx & 31];
    } else {
        int gidx = (bid - OUT_BLKS) * 256 + tid;       // coalesced W2 read
        int k = gidx >> 10, col = gidx & 1023;
        int i = col >> 5, o = col & 31;
        int s = o >> 3, n = o & 7;
        int c = n * 32 + i;
        W2k[s * 32768 + c * 128 + k] = f2bf(W2[gidx]);
    }
}

// ---------------- main kernel ----------------
__global__ __launch_bounds__(512, 2) void mpnn_kernel(const float* __restrict__ nf,
                                                      const float* __restrict__ ef,
                                                      const int*   __restrict__ esrc,
                                                      const int*   __restrict__ edst,
                                                      const float* __restrict__ W1,
                                                      const float* __restrict__ b1,
                                                      const float* __restrict__ b2,
                                                      const short* __restrict__ W2k,
                                                      float* __restrict__ out) {
    __shared__ short Hs[128 * 128];     // 32768 B  [e][k] bf16, 8-k groups XOR-swizzled by e&15
    __shared__ float Xs[128 * 36];      // 18432 B  [e][i] f32, stride 36 (bank spread)
    __shared__ short Efs[128 * 16];     //  4096 B  [e][k16] bf16, swizzled by (e>>2)&1
    __shared__ short W1Ts[128 * 16];    //  4096 B  [ch][k16] bf16, swizzled by (ch>>2)&1
    __shared__ float b1s[128];          //   512 B

    const int tid = threadIdx.x;
    const int l31 = tid & 31;
    const int lh  = (tid >> 5) & 1;     // lane>>5 within wave
    const int w   = tid >> 6;           // wave 0..7
    const int m   = w & 3;              // M-subtile (32 edges / 32 ch-rows)
    const int g   = w >> 2;             // N-group: n in [4g, 4g+4)
    const int s   = blockIdx.x & 3;     // output slice
    const int tile0 = blockIdx.x >> 2;  // 0..63

    // ---- per-block staging (once) ----
    {   // W1 [16][128] -> W1Ts[ch][k16] bf16 swizzled
        int g4 = tid * 4;
        int k16 = g4 >> 7, c0 = g4 & 127;
        float4 v = *(const float4*)(W1 + g4);
        float vv[4] = {v.x, v.y, v.z, v.w};
        int G = k16 >> 3;
        #pragma unroll
        for (int u = 0; u < 4; ++u) {
            int c = c0 + u;
            W1Ts[c * 16 + ((G ^ ((c >> 2) & 1)) << 3) + (k16 & 7)] = f2bf(vv[u]);
        }
    }
    if (tid < 128) b1s[tid] = b1[tid];

    // W2 slice panel -> registers (64 KB/block as 32 short8 per lane)
    short8 Bf[4][8];
    #pragma unroll
    for (int n = 0; n < 4; ++n) {
        int c = (4 * g + n) * 32 + l31;
        #pragma unroll
        for (int ks = 0; ks < 8; ++ks)
            Bf[n][ks] = *(const short8*)(W2k + s * 32768 + c * 128 + ks * 16 + lh * 8);
    }
    float b2v[4];   // acc init: folds b2 into the GEMM (exact fp32)
    #pragma unroll
    for (int n = 0; n < 4; ++n) b2v[n] = b2[l31 * 32 + 8 * s + 4 * g + n];

    // ---- edge-tile loop ----
    for (int t = tile0; t < N_TILES; t += 64) {
        const int ebase = t * 128;
        __syncthreads();                          // b0: prev tile's Hs/Xs/Efs reads done

        {   // ef tile -> Efs bf16 (swizzled); invalid edges -> 0
            int e = tid >> 2, k4 = (tid & 3) * 4;
            int eg = ebase + e;
            float4 v = make_float4(0.f, 0.f, 0.f, 0.f);
            if (eg < E_TOTAL) v = *(const float4*)(ef + (size_t)eg * 16 + k4);
            int G = k4 >> 3;
            s16x4 pk = { f2bf(v.x), f2bf(v.y), f2bf(v.z), f2bf(v.w) };
            *(s16x4*)(Efs + e * 16 + ((G ^ ((e >> 2) & 1)) << 3) + (k4 & 7)) = pk;
        }
        // x = nf[src] gather into registers (consumed after b1); invalid -> 0
        const int xe = tid >> 2, xq = tid & 3;
        const int xeg = ebase + xe;
        float4 xv0 = make_float4(0.f, 0.f, 0.f, 0.f), xv1 = xv0;
        if (xeg < E_TOTAL) {
            int sv = esrc[xeg];
            const float* p = nf + (size_t)sv * 32 + xq * 8;
            xv0 = *(const float4*)(p);
            xv1 = *(const float4*)(p + 4);
        }
        __syncthreads();                          // b1: Efs ready

        {   // H^T = W1T @ Ef^T : D[ch, e]; per-lane e fixed -> packed b64 Hs writes
            int ch = 32 * m + l31;
            short8 a = *(const short8*)(W1Ts + ch * 16 + ((lh ^ ((ch >> 2) & 1)) << 3));
            float4 b1q[4];
            #pragma unroll
            for (int q = 0; q < 4; ++q)
                b1q[q] = *(const float4*)(b1s + 32 * m + 8 * q + 4 * lh);
            #pragma unroll
            for (int j = 0; j < 2; ++j) {
                int nh = 2 * g + j;
                int e = 32 * nh + l31;
                short8 bfr = *(const short8*)(Efs + e * 16 + ((lh ^ ((e >> 2) & 1)) << 3));
                f32x16 hacc;
                #pragma unroll
                for (int r = 0; r < 16; ++r) hacc[r] = 0.f;
                hacc = __builtin_amdgcn_mfma_f32_32x32x16_bf16(a, bfr, hacc, 0, 0, 0);
                #pragma unroll
                for (int q = 0; q < 4; ++q) {     // ch = 32m + 8q + 4lh + (0..3)
                    float h0 = fmaxf(hacc[q * 4 + 0] + b1q[q].x, 0.f);
                    float h1 = fmaxf(hacc[q * 4 + 1] + b1q[q].y, 0.f);
                    float h2 = fmaxf(hacc[q * 4 + 2] + b1q[q].z, 0.f);
                    float h3 = fmaxf(hacc[q * 4 + 3] + b1q[q].w, 0.f);
                    s16x4 pk = { f2bf(h0), f2bf(h1), f2bf(h2), f2bf(h3) };
                    int G = 4 * m + q;
                    *(s16x4*)(Hs + e * 128 + ((G ^ (e & 15)) << 3) + 4 * lh) = pk;
                }
            }
        }
        {   // Xs write (padded stride 36)
            float* px = Xs + xe * 36 + xq * 8;
            *(float4*)(px) = xv0;
            *(float4*)(px + 4) = xv1;
        }
        __syncthreads();                          // b2: Hs, Xs ready

        // K-loop: barrier-free, B in registers, 8 A-reads + 32 MFMAs per wave
        f32x16 acc[4];
        #pragma unroll
        for (int n = 0; n < 4; ++n)
            #pragma unroll
            for (int r = 0; r < 16; ++r) acc[n][r] = b2v[n];
        #pragma unroll
        for (int ks = 0; ks < 8; ++ks) {
            int e = 32 * m + l31;
            int G = ks * 2 + lh;
            short8 a = *(const short8*)(Hs + e * 128 + ((G ^ (e & 15)) << 3));
            #pragma unroll
            for (int n = 0; n < 4; ++n)
                acc[n] = __builtin_amdgcn_mfma_f32_32x32x16_bf16(a, Bf[n][ks], acc[n], 0, 0, 0);
        }

        // contraction: msg[e, o=8s+4g+n] = sum_i x[e,i]*We[e,i,o]; i = l31
        #pragma unroll
        for (int r = 0; r < 16; ++r) {
            int e = (r & 3) + 8 * (r >> 2) + 4 * lh + 32 * m;
            float x = Xs[e * 36 + l31];
            #pragma unroll
            for (int n = 0; n < 4; ++n) {
                float v = x * acc[n][r];
                DPP_ADD(v, 0x111);                // row_shr:1
                DPP_ADD(v, 0x112);                // row_shr:2
                DPP_ADD(v, 0x114);                // row_shr:4
                DPP_ADD(v, 0x118);                // row_shr:8 -> lane15/31/47/63 = row sums
                DPP_ADD(v, 0x142);                // row_bcast15 -> lane31/63 = 32-lane sums
                if (l31 == 31) {
                    int eg2 = ebase + e;
                    int dv = (eg2 < E_TOTAL) ? edst[eg2] : 0;   // invalid e: v==0, safe
                    atomicAdd(out + (size_t)dv * 32 + 8 * s + 4 * g + n, v);
                }
            }
        }
    }
}

extern "C" void kernel_launch(void* const* d_in, const int* in_sizes, int n_in,
                              void* d_out, int out_size, void* d_ws, size_t ws_size,
                              hipStream_t stream) {
    const float* nf   = (const float*)d_in[0];
    const float* ef   = (const float*)d_in[1];
    const int*   src  = (const int*)  d_in[2];
    const int*   dst  = (const int*)  d_in[3];
    const float* W1   = (const float*)d_in[4];
    const float* b1   = (const float*)d_in[5];
    const float* W2   = (const float*)d_in[6];
    const float* b2   = (const float*)d_in[7];
    const float* bias = (const float*)d_in[8];
    float* out = (float*)d_out;
    short* W2k = (short*)d_ws;                     // 262144 B bf16 W2 panel

    setup_kernel<<<OUT_BLKS + W2K_BLKS, 256, 0, stream>>>(W2, bias, out, W2k);
    mpnn_kernel<<<256, 512, 0, stream>>>(nf, ef, src, dst, W1, b1, b2, W2k, out);
}

// Round 3
// 618.694 us; speedup vs baseline: 1.3586x; 1.3586x over previous
//
#include <hip/hip_runtime.h>

// NNConv / MPNN, round 3: register-resident W2 panel sized to fit 256 VGPRs.
//   8 output slices: slice s owns o in [4s,4s+4); panel cols c = n*32 + i.
//   Block = 256 thr (4 waves), __launch_bounds__(256,2) -> 256 VGPR cap, 2 blocks/CU.
//   Per block: Bf[4][8] short8 (128 VGPR) loaded once (coalesced, frag-major ws);
//   loop ~24 edge tiles of 128 edges:
//     ef -> B-frags DIRECT from global (no LDS stage), H^T = W1T@efT MFMA -> Hs,
//     K-loop: 8 ds_read_b128 + 32 MFMA per wave, no barriers, acc init = b2;
//     contraction: x[e,i=lane]*acc, DPP 32-lane reduce, lane31/63 -> 4 atomics.
//   2 barriers/tile. Atomics: exactly one per (e,o) = 6.4M.

#define E_TOTAL   200000
#define N_TILES   1563          // ceil(200000/128)
#define OUT_BLKS  6250          // 1600000/256
#define W2K_BLKS  512           // 131072/256

typedef short short8 __attribute__((ext_vector_type(8)));
typedef short s16x4  __attribute__((ext_vector_type(4)));
typedef float f32x16 __attribute__((ext_vector_type(16)));

__device__ __forceinline__ short f2bf(float f) {
    union { float f; unsigned u; } cv; cv.f = f;
    unsigned r = cv.u + 0x7fffu + ((cv.u >> 16) & 1u);
    return (short)(r >> 16);
}

// f32 add of DPP-shifted value; bound_ctrl=1 -> 0 for out-of-range lanes
#define DPP_ADD(v, ctrl) \
    v += __int_as_float(__builtin_amdgcn_update_dpp(0, __float_as_int(v), ctrl, 0xF, 0xF, true))

// ---------------- setup: out = bias; W2 -> bf16 frag-major panel in ws ----------------
// W2k[((s*16 + ks*2 + lh)*128 + c)*8 + kl]: s=o>>2, n=o&3, c=n*32+i, k=ks*16+lh*8+kl.
__global__ __launch_bounds__(256) void setup_kernel(const float* __restrict__ W2,
                                                    const float* __restrict__ bias,
                                                    float* __restrict__ out,
                                                    short* __restrict__ W2k) {
    int bid = blockIdx.x, tid = threadIdx.x;
    if (bid < OUT_BLKS) {
        int idx = bid * 256 + tid;
        out[idx] = bias[idx & 31];
    } else {
        int g = (bid - OUT_BLKS) * 256 + tid;          // coalesced W2 read
        int k = g >> 10, col = g & 1023;
        int i = col >> 5, o = col & 31;
        int s = o >> 2, n = o & 3, c = n * 32 + i;
        int ks = k >> 4, lh = (k >> 3) & 1, kl = k & 7;
        W2k[((s * 16 + ks * 2 + lh) * 128 + c) * 8 + kl] = f2bf(W2[g]);
    }
}

// ---------------- main kernel ----------------
__global__ __launch_bounds__(256, 2) void mpnn_kernel(const float* __restrict__ nf,
                                                      const float* __restrict__ ef,
                                                      const int*   __restrict__ esrc,
                                                      const int*   __restrict__ edst,
                                                      const float* __restrict__ W1,
                                                      const float* __restrict__ b1,
                                                      const float* __restrict__ b2,
                                                      const short* __restrict__ W2k,
                                                      float* __restrict__ out) {
    __shared__ short Hs[128 * 128];     // 32768 B [e][k] bf16, 8-k groups XOR-swizzled by e&15
    __shared__ float Xs[128 * 36];      // 18432 B [e][i] f32, stride 36
    __shared__ short W1Ts[128 * 16];    //  4096 B [ch][k16] bf16, swizzled
    __shared__ float b1s[128];          //   512 B

    const int tid = threadIdx.x;
    const int l31 = tid & 31;
    const int lh  = (tid >> 5) & 1;
    const int m   = tid >> 6;           // wave 0..3: M-subtile (32 edges / 32 ch)
    const int s   = blockIdx.x & 7;     // output slice
    const int tile0 = blockIdx.x >> 3;  // 0..63

    // ---- one-time staging ----
    {   // W1 [16][128] -> W1Ts[ch][k16] bf16 swizzled; thread handles 8 consecutive cols
        int g8 = tid * 8;
        int k16 = g8 >> 7, c0 = g8 & 127;
        float4 va = *(const float4*)(W1 + g8);
        float4 vb = *(const float4*)(W1 + g8 + 4);
        float vv[8] = {va.x, va.y, va.z, va.w, vb.x, vb.y, vb.z, vb.w};
        int G = k16 >> 3;
        #pragma unroll
        for (int u = 0; u < 8; ++u) {
            int c = c0 + u;
            W1Ts[c * 16 + ((G ^ ((c >> 2) & 1)) << 3) + (k16 & 7)] = f2bf(vv[u]);
        }
    }
    if (tid < 128) b1s[tid] = b1[tid];
    __syncthreads();

    // hoisted per-wave constants
    short8 a_w1;
    {   int ch = 32 * m + l31;
        a_w1 = *(const short8*)(W1Ts + ch * 16 + ((lh ^ ((ch >> 2) & 1)) << 3)); }
    float4 b1q[4];
    #pragma unroll
    for (int q = 0; q < 4; ++q) b1q[q] = *(const float4*)(b1s + 32 * m + 8 * q + 4 * lh);

    // W2 slice panel -> registers (coalesced frag-major reads)
    short8 Bf[4][8];
    #pragma unroll
    for (int n = 0; n < 4; ++n)
        #pragma unroll
        for (int ks = 0; ks < 8; ++ks)
            Bf[n][ks] = *(const short8*)(W2k + ((s * 16 + ks * 2 + lh) * 128 + n * 32 + l31) * 8);
    float b2v[4];
    #pragma unroll
    for (int n = 0; n < 4; ++n) b2v[n] = b2[l31 * 32 + 4 * s + n];

    // ---- edge-tile loop ----
    for (int t = tile0; t < N_TILES; t += 64) {
        const int ebase = t * 128;
        __syncthreads();                         // b0: prev tile's Hs/Xs reads done

        // ef -> B-frag registers (direct global; frag = 8 consecutive k of row e)
        float4 ef0[4], ef1[4];
        #pragma unroll
        for (int j = 0; j < 4; ++j) {
            ef0[j] = make_float4(0.f, 0.f, 0.f, 0.f);
            ef1[j] = ef0[j];
            int eg = ebase + 32 * j + l31;
            if (eg < E_TOTAL) {
                const float* p = ef + (size_t)eg * 16 + 8 * lh;
                ef0[j] = *(const float4*)(p);
                ef1[j] = *(const float4*)(p + 4);
            }
        }
        // nf gather into registers
        const int xe = tid >> 1, xh = tid & 1, xeg = ebase + xe;
        float4 xv0 = make_float4(0.f, 0.f, 0.f, 0.f), xv1 = xv0, xv2 = xv0, xv3 = xv0;
        if (xeg < E_TOTAL) {
            const float* p = nf + (size_t)esrc[xeg] * 32 + xh * 16;
            xv0 = *(const float4*)(p);      xv1 = *(const float4*)(p + 4);
            xv2 = *(const float4*)(p + 8);  xv3 = *(const float4*)(p + 12);
        }

        // H^T = W1T @ ef^T; D[ch, e], per-lane e fixed -> packed b64 Hs writes
        #pragma unroll
        for (int j = 0; j < 4; ++j) {
            short8 bfr = { f2bf(ef0[j].x), f2bf(ef0[j].y), f2bf(ef0[j].z), f2bf(ef0[j].w),
                           f2bf(ef1[j].x), f2bf(ef1[j].y), f2bf(ef1[j].z), f2bf(ef1[j].w) };
            f32x16 hacc;
            #pragma unroll
            for (int r = 0; r < 16; ++r) hacc[r] = 0.f;
            hacc = __builtin_amdgcn_mfma_f32_32x32x16_bf16(a_w1, bfr, hacc, 0, 0, 0);
            int e2 = 32 * j + l31;
            #pragma unroll
            for (int q = 0; q < 4; ++q) {        // ch = 32m + 8q + 4lh + u
                float h0 = fmaxf(hacc[q * 4 + 0] + b1q[q].x, 0.f);
                float h1 = fmaxf(hacc[q * 4 + 1] + b1q[q].y, 0.f);
                float h2 = fmaxf(hacc[q * 4 + 2] + b1q[q].z, 0.f);
                float h3 = fmaxf(hacc[q * 4 + 3] + b1q[q].w, 0.f);
                s16x4 pk = { f2bf(h0), f2bf(h1), f2bf(h2), f2bf(h3) };
                int G = 4 * m + q;
                *(s16x4*)(Hs + e2 * 128 + ((G ^ (e2 & 15)) << 3) + 4 * lh) = pk;
            }
        }
        {   // Xs write
            float* px = Xs + xe * 36 + xh * 16;
            *(float4*)(px)      = xv0;  *(float4*)(px + 4)  = xv1;
            *(float4*)(px + 8)  = xv2;  *(float4*)(px + 12) = xv3;
        }
        __syncthreads();                         // b1: Hs, Xs ready

        // K-loop: barrier-free, B in registers; 8 A-reads + 32 MFMAs per wave
        f32x16 acc[4];
        #pragma unroll
        for (int n = 0; n < 4; ++n)
            #pragma unroll
            for (int r = 0; r < 16; ++r) acc[n][r] = b2v[n];
        #pragma unroll
        for (int ks = 0; ks < 8; ++ks) {
            int e = 32 * m + l31;
            int G = ks * 2 + lh;
            short8 a = *(const short8*)(Hs + e * 128 + ((G ^ (e & 15)) << 3));
            #pragma unroll
            for (int n = 0; n < 4; ++n)
                acc[n] = __builtin_amdgcn_mfma_f32_32x32x16_bf16(a, Bf[n][ks], acc[n], 0, 0, 0);
        }

        // contraction: msg[e, o=4s+n] = sum_i x[e,i]*We[e,i,o]; i = l31
        #pragma unroll
        for (int r = 0; r < 16; ++r) {
            int e = (r & 3) + 8 * (r >> 2) + 4 * lh + 32 * m;
            float x = Xs[e * 36 + l31];
            float vr[4];
            #pragma unroll
            for (int n = 0; n < 4; ++n) {
                float v = x * acc[n][r];
                DPP_ADD(v, 0x111);               // row_shr:1
                DPP_ADD(v, 0x112);               // row_shr:2
                DPP_ADD(v, 0x114);               // row_shr:4
                DPP_ADD(v, 0x118);               // row_shr:8 -> lane15/31 of each row
                DPP_ADD(v, 0x142);               // row_bcast15 -> lane31/63 = 32-lane sums
                vr[n] = v;
            }
            if (l31 == 31) {
                int eg2 = ebase + e;
                int dv = (eg2 < E_TOTAL) ? edst[eg2] : 0;    // invalid e: vr==0, safe
                float* po = out + (size_t)dv * 32 + 4 * s;
                atomicAdd(po + 0, vr[0]);
                atomicAdd(po + 1, vr[1]);
                atomicAdd(po + 2, vr[2]);
                atomicAdd(po + 3, vr[3]);
            }
        }
    }
}

extern "C" void kernel_launch(void* const* d_in, const int* in_sizes, int n_in,
                              void* d_out, int out_size, void* d_ws, size_t ws_size,
                              hipStream_t stream) {
    const float* nf   = (const float*)d_in[0];
    const float* ef   = (const float*)d_in[1];
    const int*   src  = (const int*)  d_in[2];
    const int*   dst  = (const int*)  d_in[3];
    const float* W1   = (const float*)d_in[4];
    const float* b1   = (const float*)d_in[5];
    const float* W2   = (const float*)d_in[6];
    const float* b2   = (const float*)d_in[7];
    const float* bias = (const float*)d_in[8];
    float* out = (float*)d_out;
    short* W2k = (short*)d_ws;                     // 262144 B bf16 W2 panel (frag-major)

    setup_kernel<<<OUT_BLKS + W2K_BLKS, 256, 0, stream>>>(W2, bias, out, W2k);
    mpnn_kernel<<<512, 256, 0, stream>>>(nf, ef, src, dst, W1, b1, b2, W2k, out);
}

// Round 4
// 610.612 us; speedup vs baseline: 1.3765x; 1.0132x over previous
//
#include <hip/hip_runtime.h>
#include <hip/hip_bf16.h>

// NNConv / MPNN, round 4: register panel sized to the REAL arch-VGPR budget.
//   Evidence r2/r3: __launch_bounds__(256,2) yields ~128 ARCH VGPRs (256 total,
//   arch/acc split); Bf[4][8]=128 arch busted it -> spills. Now:
//   16 output slices: slice s owns o in {2s,2s+1}; Bf[2][8] short8 = 64 arch.
//   Grid = 16 slices x 32 tile-groups = 512 blocks = 2/CU, all co-resident.
//   Per tile: ef -> B-frags direct (packed cvt), H^T = W1T@efT MFMA (C-init = b1,
//   relu + packed bf16 cvt -> Hs), K-loop 8 ds_read_b128 + 16 MFMA (acc init b2),
//   contraction x*We with DPP 32-lane reduce, lane31/63 -> 2 atomics each.
//   2 barriers/tile. Atomics: exactly one per (e,o) = 6.4M.

#define E_TOTAL   200000
#define N_TILES   1563          // ceil(200000/128)
#define OUT_BLKS  6250          // 1600000/256
#define W2K_BLKS  512           // 131072/256

typedef short short8 __attribute__((ext_vector_type(8)));
typedef float f32x16 __attribute__((ext_vector_type(16)));

__device__ __forceinline__ unsigned pkbf(float a, float b) {
    union { __hip_bfloat162 h; unsigned u; } cv;
    cv.h = __float22bfloat162_rn(make_float2(a, b));   // v_cvt_pk_bf16_f32 (RNE)
    return cv.u;
}
__device__ __forceinline__ short f2bf(float f) {
    union { float f; unsigned u; } cv; cv.f = f;
    unsigned r = cv.u + 0x7fffu + ((cv.u >> 16) & 1u);
    return (short)(r >> 16);
}

// f32 add of DPP-shifted value; bound_ctrl=1 -> 0 for out-of-range lanes
#define DPP_ADD(v, ctrl) \
    v += __int_as_float(__builtin_amdgcn_update_dpp(0, __float_as_int(v), ctrl, 0xF, 0xF, true))

// ---------------- setup: out = bias; W2 -> bf16 frag-major panel in ws ----------------
// W2k[((s*16 + ks*2 + lh)*64 + c)*8 + kl]: s=o>>1, n=o&1, c=n*32+i, k=ks*16+lh*8+kl.
__global__ __launch_bounds__(256) void setup_kernel(const float* __restrict__ W2,
                                                    const float* __restrict__ bias,
                                                    float* __restrict__ out,
                                                    short* __restrict__ W2k) {
    int bid = blockIdx.x, tid = threadIdx.x;
    if (bid < OUT_BLKS) {
        int idx = bid * 256 + tid;
        out[idx] = bias[idx & 31];
    } else {
        int g = (bid - OUT_BLKS) * 256 + tid;          // coalesced W2 read
        int k = g >> 10, col = g & 1023;
        int i = col >> 5, o = col & 31;
        int s = o >> 1, n = o & 1, c = n * 32 + i;
        int ks = k >> 4, lh = (k >> 3) & 1, kl = k & 7;
        W2k[((s * 16 + ks * 2 + lh) * 64 + c) * 8 + kl] = f2bf(W2[g]);
    }
}

// ---------------- main kernel ----------------
__global__ __launch_bounds__(256, 2) void mpnn_kernel(const float* __restrict__ nf,
                                                      const float* __restrict__ ef,
                                                      const int*   __restrict__ esrc,
                                                      const int*   __restrict__ edst,
                                                      const float* __restrict__ W1,
                                                      const float* __restrict__ b1,
                                                      const float* __restrict__ b2,
                                                      const short* __restrict__ W2k,
                                                      float* __restrict__ out) {
    __shared__ short Hs[128 * 128];     // 32768 B [e][k] bf16, 8-k groups XOR-swizzled by e&15
    __shared__ float Xs[128 * 36];      // 18432 B [e][i] f32, stride 36
    __shared__ short W1Ts[128 * 16];    //  4096 B [ch][k16] bf16, swizzled
    __shared__ float b1s[128];          //   512 B

    const int tid = threadIdx.x;
    const int l31 = tid & 31;
    const int lh  = (tid >> 5) & 1;
    const int m   = tid >> 6;           // wave 0..3: M-subtile (32 edges / 32 ch)
    const int s   = blockIdx.x & 15;    // output slice: o in {2s, 2s+1}
    const int g0  = blockIdx.x >> 4;    // tile group 0..31

    // ---- one-time staging ----
    {   // W1 [16][128] -> W1Ts[ch][k16] bf16 swizzled; thread handles 8 consecutive cols
        int g8 = tid * 8;
        int k16 = g8 >> 7, c0 = g8 & 127;
        float4 va = *(const float4*)(W1 + g8);
        float4 vb = *(const float4*)(W1 + g8 + 4);
        float vv[8] = {va.x, va.y, va.z, va.w, vb.x, vb.y, vb.z, vb.w};
        int G = k16 >> 3;
        #pragma unroll
        for (int u = 0; u < 8; ++u) {
            int c = c0 + u;
            W1Ts[c * 16 + ((G ^ ((c >> 2) & 1)) << 3) + (k16 & 7)] = f2bf(vv[u]);
        }
    }
    if (tid < 128) b1s[tid] = b1[tid];
    __syncthreads();

    // hoisted per-wave constants
    short8 a_w1;
    {   int ch = 32 * m + l31;
        a_w1 = *(const short8*)(W1Ts + ch * 16 + ((lh ^ ((ch >> 2) & 1)) << 3)); }
    f32x16 hinit;                       // b1 folded into H-MFMA C-init
    #pragma unroll
    for (int r = 0; r < 16; ++r) hinit[r] = b1s[32 * m + 8 * (r >> 2) + 4 * lh + (r & 3)];

    // W2 slice panel -> registers (coalesced frag-major reads): 64 arch VGPRs
    short8 Bf[2][8];
    #pragma unroll
    for (int n = 0; n < 2; ++n)
        #pragma unroll
        for (int ks = 0; ks < 8; ++ks)
            Bf[n][ks] = *(const short8*)(W2k + ((s * 16 + ks * 2 + lh) * 64 + n * 32 + l31) * 8);
    const float b2v0 = b2[l31 * 32 + 2 * s];
    const float b2v1 = b2[l31 * 32 + 2 * s + 1];

    // ---- edge-tile loop ----
    for (int t = g0; t < N_TILES; t += 32) {
        const int ebase = t * 128;
        __syncthreads();                         // b0: prev tile's Hs/Xs reads done

        // ef -> B-frag registers (direct global; frag = 8 consecutive k of row e)
        short8 bfr[4];
        #pragma unroll
        for (int j = 0; j < 4; ++j) {
            int eg = ebase + 32 * j + l31;
            float4 v0 = make_float4(0.f, 0.f, 0.f, 0.f), v1 = v0;
            if (eg < E_TOTAL) {
                const float* p = ef + (size_t)eg * 16 + 8 * lh;
                v0 = *(const float4*)(p);
                v1 = *(const float4*)(p + 4);
            }
            union { unsigned u[4]; short8 s8; } cv;
            cv.u[0] = pkbf(v0.x, v0.y); cv.u[1] = pkbf(v0.z, v0.w);
            cv.u[2] = pkbf(v1.x, v1.y); cv.u[3] = pkbf(v1.z, v1.w);
            bfr[j] = cv.s8;
        }
        // nf gather into registers
        const int xe = tid >> 1, xh = tid & 1, xeg = ebase + xe;
        float4 xv0 = make_float4(0.f, 0.f, 0.f, 0.f), xv1 = xv0, xv2 = xv0, xv3 = xv0;
        if (xeg < E_TOTAL) {
            const float* p = nf + (size_t)esrc[xeg] * 32 + xh * 16;
            xv0 = *(const float4*)(p);      xv1 = *(const float4*)(p + 4);
            xv2 = *(const float4*)(p + 8);  xv3 = *(const float4*)(p + 12);
        }

        // H^T = W1T @ ef^T; C-init = b1; relu + packed cvt -> Hs (b64 writes)
        #pragma unroll
        for (int j = 0; j < 4; ++j) {
            f32x16 hacc = hinit;
            hacc = __builtin_amdgcn_mfma_f32_32x32x16_bf16(a_w1, bfr[j], hacc, 0, 0, 0);
            int e2 = 32 * j + l31;
            #pragma unroll
            for (int q = 0; q < 4; ++q) {        // ch = 32m + 8q + 4lh + u
                float h0 = fmaxf(hacc[q * 4 + 0], 0.f);
                float h1 = fmaxf(hacc[q * 4 + 1], 0.f);
                float h2 = fmaxf(hacc[q * 4 + 2], 0.f);
                float h3 = fmaxf(hacc[q * 4 + 3], 0.f);
                uint2 pk = { pkbf(h0, h1), pkbf(h2, h3) };
                int G = 4 * m + q;
                *(uint2*)(Hs + e2 * 128 + ((G ^ (e2 & 15)) << 3) + 4 * lh) = pk;
            }
        }
        {   // Xs write
            float* px = Xs + xe * 36 + xh * 16;
            *(float4*)(px)      = xv0;  *(float4*)(px + 4)  = xv1;
            *(float4*)(px + 8)  = xv2;  *(float4*)(px + 12) = xv3;
        }
        __syncthreads();                         // b1: Hs, Xs ready

        // K-loop: barrier-free, B in registers; 8 A-reads + 16 MFMAs per wave
        f32x16 acc[2];
        #pragma unroll
        for (int r = 0; r < 16; ++r) { acc[0][r] = b2v0; acc[1][r] = b2v1; }
        #pragma unroll
        for (int ks = 0; ks < 8; ++ks) {
            int e = 32 * m + l31;
            int G = ks * 2 + lh;
            short8 a = *(const short8*)(Hs + e * 128 + ((G ^ (e & 15)) << 3));
            acc[0] = __builtin_amdgcn_mfma_f32_32x32x16_bf16(a, Bf[0][ks], acc[0], 0, 0, 0);
            acc[1] = __builtin_amdgcn_mfma_f32_32x32x16_bf16(a, Bf[1][ks], acc[1], 0, 0, 0);
        }

        // contraction: msg[e, o=2s+n] = sum_i x[e,i]*We[e,i,o]; i = l31
        #pragma unroll
        for (int r = 0; r < 16; ++r) {
            int e = (r & 3) + 8 * (r >> 2) + 4 * lh + 32 * m;
            float x = Xs[e * 36 + l31];
            float v0 = x * acc[0][r];
            float v1 = x * acc[1][r];
            DPP_ADD(v0, 0x111); DPP_ADD(v1, 0x111);   // row_shr:1
            DPP_ADD(v0, 0x112); DPP_ADD(v1, 0x112);   // row_shr:2
            DPP_ADD(v0, 0x114); DPP_ADD(v1, 0x114);   // row_shr:4
            DPP_ADD(v0, 0x118); DPP_ADD(v1, 0x118);   // row_shr:8
            DPP_ADD(v0, 0x142); DPP_ADD(v1, 0x142);   // row_bcast15 -> lane31/63
            if (l31 == 31) {
                int eg2 = ebase + e;
                int dv = (eg2 < E_TOTAL) ? edst[eg2] : 0;    // invalid e: x=0 -> v=0, safe
                float* po = out + (size_t)dv * 32 + 2 * s;
                atomicAdd(po + 0, v0);
                atomicAdd(po + 1, v1);
            }
        }
    }
}

extern "C" void kernel_launch(void* const* d_in, const int* in_sizes, int n_in,
                              void* d_out, int out_size, void* d_ws, size_t ws_size,
                              hipStream_t stream) {
    const float* nf   = (const float*)d_in[0];
    const float* ef   = (const float*)d_in[1];
    const int*   src  = (const int*)  d_in[2];
    const int*   dst  = (const int*)  d_in[3];
    const float* W1   = (const float*)d_in[4];
    const float* b1   = (const float*)d_in[5];
    const float* W2   = (const float*)d_in[6];
    const float* b2   = (const float*)d_in[7];
    const float* bias = (const float*)d_in[8];
    float* out = (float*)d_out;
    short* W2k = (short*)d_ws;                     // 262144 B bf16 W2 panel (frag-major)

    setup_kernel<<<OUT_BLKS + W2K_BLKS, 256, 0, stream>>>(W2, bias, out, W2k);
    mpnn_kernel<<<512, 256, 0, stream>>>(nf, ef, src, dst, W1, b1, b2, W2k, out);
}

// Round 5
// 610.175 us; speedup vs baseline: 1.3775x; 1.0007x over previous
//
#include <hip/hip_runtime.h>
#include <hip/hip_bf16.h>

// NNConv / MPNN, round 5: decoupled barrier-free pipeline.
//   setup : out = bias; W2 -> bf16 frag-major panel W2k (256 KB, ws).
//   hfeat : H = relu(ef@W1+b1) computed ONCE, stored bf16 to ws in the MFMA
//           A-frag layout [tile32][G=k>>3][e32][kl8] -- transpose via layout,
//           no per-tile LDS/barriers.
//   msg   : per (32-edge tile, slice s of 16): Bf[2][8] W2-panel in regs,
//           A-frags via coalesced global loads from Hws, K-loop 16 MFMA,
//           contraction with x rows read from nf (lane = i), DPP 32-lane
//           reduce, lanes 31/63 fire atomics. ZERO LDS, ZERO barriers ->
//           atomic drain and gather latency fully overlapped by occupancy.
//   ws layout: [0,256K) W2k | [256K, 256K+51.2M) Hws (200064 rows padded).

#define E_TOTAL   200000
#define A_TILES   1563          // ceil(200000/128) 128-edge tiles (kernel A)
#define B_TILES   6250          // 200000/32 32-edge tiles (kernel B), exact
#define OUT_BLKS  6250          // 1600000/256
#define W2K_BLKS  512           // 131072/256
#define HWS_OFF   131072        // shorts: 262144 B / 2

typedef short short8 __attribute__((ext_vector_type(8)));
typedef float f32x16 __attribute__((ext_vector_type(16)));

__device__ __forceinline__ unsigned pkbf(float a, float b) {
    union { __hip_bfloat162 h; unsigned u; } cv;
    cv.h = __float22bfloat162_rn(make_float2(a, b));   // v_cvt_pk_bf16_f32 (RNE)
    return cv.u;
}
__device__ __forceinline__ short f2bf(float f) {
    union { float f; unsigned u; } cv; cv.f = f;
    unsigned r = cv.u + 0x7fffu + ((cv.u >> 16) & 1u);
    return (short)(r >> 16);
}

// f32 add of DPP-shifted value; bound_ctrl=1 -> 0 for out-of-range lanes
#define DPP_ADD(v, ctrl) \
    v += __int_as_float(__builtin_amdgcn_update_dpp(0, __float_as_int(v), ctrl, 0xF, 0xF, true))

// ---------------- setup: out = bias; W2 -> bf16 frag-major panel ----------------
// W2k[((s*16 + ks*2 + lh)*64 + c)*8 + kl]: s=o>>1, n=o&1, c=n*32+i, k=ks*16+lh*8+kl.
__global__ __launch_bounds__(256) void setup_kernel(const float* __restrict__ W2,
                                                    const float* __restrict__ bias,
                                                    float* __restrict__ out,
                                                    short* __restrict__ W2k) {
    int bid = blockIdx.x, tid = threadIdx.x;
    if (bid < OUT_BLKS) {
        int idx = bid * 256 + tid;
        out[idx] = bias[idx & 31];
    } else {
        int g = (bid - OUT_BLKS) * 256 + tid;          // coalesced W2 read
        int k = g >> 10, col = g & 1023;
        int i = col >> 5, o = col & 31;
        int s = o >> 1, n = o & 1, c = n * 32 + i;
        int ks = k >> 4, lh = (k >> 3) & 1, kl = k & 7;
        W2k[((s * 16 + ks * 2 + lh) * 64 + c) * 8 + kl] = f2bf(W2[g]);
    }
}

// ---------------- kernel A: H once, stored in A-frag layout ----------------
// Hws[((tile32*16 + G)*32 + e32)*8 + kl], G = ch>>3, kl = ch&7, ch = k of H.
__global__ __launch_bounds__(256) void hfeat_kernel(const float* __restrict__ ef,
                                                    const float* __restrict__ W1,
                                                    const float* __restrict__ b1,
                                                    short* __restrict__ Hws) {
    __shared__ short W1Ts[128 * 16];    // [ch][k16] bf16, swizzled
    __shared__ float b1s[128];

    const int tid = threadIdx.x;
    const int l31 = tid & 31;
    const int lh  = (tid >> 5) & 1;
    const int m   = tid >> 6;           // wave: ch-subtile 32m..32m+31

    {   // W1 [16][128] -> W1Ts bf16 swizzled
        int g8 = tid * 8;
        int k16 = g8 >> 7, c0 = g8 & 127;
        float4 va = *(const float4*)(W1 + g8);
        float4 vb = *(const float4*)(W1 + g8 + 4);
        float vv[8] = {va.x, va.y, va.z, va.w, vb.x, vb.y, vb.z, vb.w};
        int G = k16 >> 3;
        #pragma unroll
        for (int u = 0; u < 8; ++u) {
            int c = c0 + u;
            W1Ts[c * 16 + ((G ^ ((c >> 2) & 1)) << 3) + (k16 & 7)] = f2bf(vv[u]);
        }
    }
    if (tid < 128) b1s[tid] = b1[tid];
    __syncthreads();                    // only barrier in this kernel

    short8 a_w1;
    {   int ch = 32 * m + l31;
        a_w1 = *(const short8*)(W1Ts + ch * 16 + ((lh ^ ((ch >> 2) & 1)) << 3)); }
    f32x16 hinit;
    #pragma unroll
    for (int r = 0; r < 16; ++r) hinit[r] = b1s[32 * m + 8 * (r >> 2) + 4 * lh + (r & 3)];

    for (int t = blockIdx.x; t < A_TILES; t += gridDim.x) {
        const int ebase = t * 128;
        #pragma unroll
        for (int j = 0; j < 4; ++j) {
            int eg = ebase + 32 * j + l31;
            float4 v0 = make_float4(0.f, 0.f, 0.f, 0.f), v1 = v0;
            if (eg < E_TOTAL) {
                const float* p = ef + (size_t)eg * 16 + 8 * lh;
                v0 = *(const float4*)(p);
                v1 = *(const float4*)(p + 4);
            }
            union { unsigned u[4]; short8 s8; } cv;
            cv.u[0] = pkbf(v0.x, v0.y); cv.u[1] = pkbf(v0.z, v0.w);
            cv.u[2] = pkbf(v1.x, v1.y); cv.u[3] = pkbf(v1.z, v1.w);

            f32x16 hacc = hinit;
            hacc = __builtin_amdgcn_mfma_f32_32x32x16_bf16(a_w1, cv.s8, hacc, 0, 0, 0);
            // lane holds H[ch = 32m+8q+4lh+u][e = 32j+l31]; store A-frag layout
            #pragma unroll
            for (int q = 0; q < 4; ++q) {
                float h0 = fmaxf(hacc[q * 4 + 0], 0.f);
                float h1 = fmaxf(hacc[q * 4 + 1], 0.f);
                float h2 = fmaxf(hacc[q * 4 + 2], 0.f);
                float h3 = fmaxf(hacc[q * 4 + 3], 0.f);
                uint2 pk = { pkbf(h0, h1), pkbf(h2, h3) };
                size_t idx = ((size_t)((t * 4 + j) * 16 + 4 * m + q) * 32 + l31) * 8 + 4 * lh;
                *(uint2*)(Hws + idx) = pk;     // coalesced 1 KB per (j,q) per wave
            }
        }
    }
}

// ---------------- kernel B: msg + aggregation; no LDS, no barriers ----------------
__global__ __launch_bounds__(256) void msg_kernel(const float* __restrict__ nf,
                                                  const int*   __restrict__ esrc,
                                                  const int*   __restrict__ edst,
                                                  const float* __restrict__ b2,
                                                  const short* __restrict__ W2k,
                                                  const short* __restrict__ Hws,
                                                  float* __restrict__ out) {
    const int tid = threadIdx.x;
    const int l31 = tid & 31;
    const int lh  = (tid >> 5) & 1;
    const int w   = tid >> 6;
    const int s   = ((blockIdx.x & 3) << 2) + w;   // slice 0..15: o in {2s,2s+1}
    const int tg  = blockIdx.x >> 2;               // tile group 0..1023

    // W2 slice panel -> registers (64 arch VGPRs), loaded once per block
    short8 Bf[2][8];
    #pragma unroll
    for (int n = 0; n < 2; ++n)
        #pragma unroll
        for (int ks = 0; ks < 8; ++ks)
            Bf[n][ks] = *(const short8*)(W2k + ((s * 16 + ks * 2 + lh) * 64 + n * 32 + l31) * 8);
    const float b2v0 = b2[l31 * 32 + 2 * s];
    const float b2v1 = b2[l31 * 32 + 2 * s + 1];

    for (int t = tg; t < B_TILES; t += 1024) {
        const int ebase = t * 32;
        // edge indices: lanes 0..31 hold e0..e31 (upper half duplicates)
        const int srcv = esrc[ebase + l31];
        const int dstv = edst[ebase + l31];

        // K-loop: A-frags straight from Hws (coalesced dwordx4), B in regs
        f32x16 acc[2];
        #pragma unroll
        for (int r = 0; r < 16; ++r) { acc[0][r] = b2v0; acc[1][r] = b2v1; }
        #pragma unroll
        for (int ks = 0; ks < 8; ++ks) {
            short8 a = *(const short8*)(Hws + ((size_t)(t * 16 + ks * 2 + lh) * 32 + l31) * 8);
            acc[0] = __builtin_amdgcn_mfma_f32_32x32x16_bf16(a, Bf[0][ks], acc[0], 0, 0, 0);
            acc[1] = __builtin_amdgcn_mfma_f32_32x32x16_bf16(a, Bf[1][ks], acc[1], 0, 0, 0);
        }

        // contraction: msg[e, 2s+n] = sum_i x[e,i]*We[e,i,2s+n]; i = l31
        #pragma unroll
        for (int r = 0; r < 16; ++r) {
            int e  = (r & 3) + 8 * (r >> 2) + 4 * lh;          // 0..31
            int sv = __shfl(srcv, e);
            int dv = __shfl(dstv, e);
            float x = nf[(size_t)sv * 32 + l31];               // row-coalesced
            float v0 = x * acc[0][r];
            float v1 = x * acc[1][r];
            DPP_ADD(v0, 0x111); DPP_ADD(v1, 0x111);            // row_shr:1
            DPP_ADD(v0, 0x112); DPP_ADD(v1, 0x112);            // row_shr:2
            DPP_ADD(v0, 0x114); DPP_ADD(v1, 0x114);            // row_shr:4
            DPP_ADD(v0, 0x118); DPP_ADD(v1, 0x118);            // row_shr:8
            DPP_ADD(v0, 0x142); DPP_ADD(v1, 0x142);            // row_bcast15 -> lane31/63
            if (l31 == 31) {
                float* po = out + (size_t)dv * 32 + 2 * s;
                atomicAdd(po + 0, v0);
                atomicAdd(po + 1, v1);
            }
        }
    }
}

extern "C" void kernel_launch(void* const* d_in, const int* in_sizes, int n_in,
                              void* d_out, int out_size, void* d_ws, size_t ws_size,
                              hipStream_t stream) {
    const float* nf   = (const float*)d_in[0];
    const float* ef   = (const float*)d_in[1];
    const int*   src  = (const int*)  d_in[2];
    const int*   dst  = (const int*)  d_in[3];
    const float* W1   = (const float*)d_in[4];
    const float* b1   = (const float*)d_in[5];
    const float* W2   = (const float*)d_in[6];
    const float* b2   = (const float*)d_in[7];
    const float* bias = (const float*)d_in[8];
    float* out = (float*)d_out;
    short* W2k = (short*)d_ws;                 // 262144 B
    short* Hws = W2k + HWS_OFF;                // 51.2 MB bf16 H, A-frag layout

    setup_kernel<<<OUT_BLKS + W2K_BLKS, 256, 0, stream>>>(W2, bias, out, W2k);
    hfeat_kernel<<<512, 256, 0, stream>>>(ef, W1, b1, Hws);
    msg_kernel<<<4096, 256, 0, stream>>>(nf, src, dst, b2, W2k, Hws, out);
}

// Round 6
// 506.377 us; speedup vs baseline: 1.6599x; 1.2050x over previous
//
#include <hip/hip_runtime.h>
#include <hip/hip_bf16.h>

// NNConv / MPNN, round 6: sector-dense atomics.
//   Evidence r5: WRITE_SIZE = 6.4M x 32 B exactly -- every 2-lane atomic instr
//   RMWs a full 32 B HBM sector (coalescing happens only within one instr's
//   lanes; r1's dense atomics measured 6.4M x 4 B). Fix: block quad c covers
//   o in [8c,8c+8); DPP results go to a 1 KB LDS msgbuf[32e][8o]; 256 threads
//   then fire one atomic each, 8 consecutive lanes = one full 32 B sector.
//   prep  : out=bias | W2->bf16 frag-major W2k | H=relu(ef@W1+b1) once, bf16,
//           stored straight from MFMA regs in A-frag layout (one fused kernel).
//   msg   : per (32-edge tile, quad c): wave w = slice s=4c+w, Bf[2][8] panel
//           in regs, A-frags from Hws, 16 MFMA, DPP 32-lane reduce,
//           LDS transpose, sector-dense atomics. 2 barriers/tile.

#define E_TOTAL   200000
#define A_TILES   1563          // ceil(200000/128) hfeat tiles
#define B_TILES   6250          // 200000/32 msg tiles (exact)
#define OUT_BLKS  6250          // 1600000/256
#define W2K_BLKS  512           // 131072/256
#define HWS_OFF   131072        // shorts: 262144 B / 2

typedef short short8 __attribute__((ext_vector_type(8)));
typedef float f32x16 __attribute__((ext_vector_type(16)));

__device__ __forceinline__ unsigned pkbf(float a, float b) {
    union { __hip_bfloat162 h; unsigned u; } cv;
    cv.h = __float22bfloat162_rn(make_float2(a, b));   // v_cvt_pk_bf16_f32 (RNE)
    return cv.u;
}
__device__ __forceinline__ short f2bf(float f) {
    union { float f; unsigned u; } cv; cv.f = f;
    unsigned r = cv.u + 0x7fffu + ((cv.u >> 16) & 1u);
    return (short)(r >> 16);
}

// f32 add of DPP-shifted value; bound_ctrl=1 -> 0 for out-of-range lanes
#define DPP_ADD(v, ctrl) \
    v += __int_as_float(__builtin_amdgcn_update_dpp(0, __float_as_int(v), ctrl, 0xF, 0xF, true))

// ---------------- prep: out=bias | W2 panel | H in A-frag layout ----------------
// W2k[((s*16 + ks*2 + lh)*64 + c)*8 + kl]: s=o>>1, n=o&1, c=n*32+i, k=ks*16+lh*8+kl.
// Hws[((tile32*16 + G)*32 + e32)*8 + kl], G = ch>>3, kl = ch&7 (A-frag layout).
__global__ __launch_bounds__(256) void prep_kernel(const float* __restrict__ ef,
                                                   const float* __restrict__ W1,
                                                   const float* __restrict__ b1,
                                                   const float* __restrict__ W2,
                                                   const float* __restrict__ bias,
                                                   float* __restrict__ out,
                                                   short* __restrict__ W2k,
                                                   short* __restrict__ Hws) {
    __shared__ short W1Ts[128 * 16];
    __shared__ float b1s[128];
    const int bid = blockIdx.x, tid = threadIdx.x;

    if (bid < OUT_BLKS) {                       // out = bias
        int idx = bid * 256 + tid;
        out[idx] = bias[idx & 31];
        return;
    }
    if (bid < OUT_BLKS + W2K_BLKS) {            // W2 -> frag-major bf16 panel
        int g = (bid - OUT_BLKS) * 256 + tid;
        int k = g >> 10, col = g & 1023;
        int i = col >> 5, o = col & 31;
        int s = o >> 1, n = o & 1, c = n * 32 + i;
        int ks = k >> 4, lh = (k >> 3) & 1, kl = k & 7;
        W2k[((s * 16 + ks * 2 + lh) * 64 + c) * 8 + kl] = f2bf(W2[g]);
        return;
    }
    // ---- hfeat: one 128-edge tile per block ----
    const int t   = bid - (OUT_BLKS + W2K_BLKS);
    const int l31 = tid & 31;
    const int lh  = (tid >> 5) & 1;
    const int m   = tid >> 6;

    {   // W1 [16][128] -> W1Ts bf16 swizzled
        int g8 = tid * 8;
        int k16 = g8 >> 7, c0 = g8 & 127;
        float4 va = *(const float4*)(W1 + g8);
        float4 vb = *(const float4*)(W1 + g8 + 4);
        float vv[8] = {va.x, va.y, va.z, va.w, vb.x, vb.y, vb.z, vb.w};
        int G = k16 >> 3;
        #pragma unroll
        for (int u = 0; u < 8; ++u) {
            int c = c0 + u;
            W1Ts[c * 16 + ((G ^ ((c >> 2) & 1)) << 3) + (k16 & 7)] = f2bf(vv[u]);
        }
    }
    if (tid < 128) b1s[tid] = b1[tid];
    __syncthreads();

    short8 a_w1;
    {   int ch = 32 * m + l31;
        a_w1 = *(const short8*)(W1Ts + ch * 16 + ((lh ^ ((ch >> 2) & 1)) << 3)); }
    f32x16 hinit;
    #pragma unroll
    for (int r = 0; r < 16; ++r) hinit[r] = b1s[32 * m + 8 * (r >> 2) + 4 * lh + (r & 3)];

    const int ebase = t * 128;
    #pragma unroll
    for (int j = 0; j < 4; ++j) {
        int eg = ebase + 32 * j + l31;
        float4 v0 = make_float4(0.f, 0.f, 0.f, 0.f), v1 = v0;
        if (eg < E_TOTAL) {
            const float* p = ef + (size_t)eg * 16 + 8 * lh;
            v0 = *(const float4*)(p);
            v1 = *(const float4*)(p + 4);
        }
        union { unsigned u[4]; short8 s8; } cv;
        cv.u[0] = pkbf(v0.x, v0.y); cv.u[1] = pkbf(v0.z, v0.w);
        cv.u[2] = pkbf(v1.x, v1.y); cv.u[3] = pkbf(v1.z, v1.w);

        f32x16 hacc = hinit;
        hacc = __builtin_amdgcn_mfma_f32_32x32x16_bf16(a_w1, cv.s8, hacc, 0, 0, 0);
        // lane holds H[ch = 32m+8q+4lh+u][e = 32j+l31]; store in A-frag layout
        #pragma unroll
        for (int q = 0; q < 4; ++q) {
            float h0 = fmaxf(hacc[q * 4 + 0], 0.f);
            float h1 = fmaxf(hacc[q * 4 + 1], 0.f);
            float h2 = fmaxf(hacc[q * 4 + 2], 0.f);
            float h3 = fmaxf(hacc[q * 4 + 3], 0.f);
            uint2 pk = { pkbf(h0, h1), pkbf(h2, h3) };
            size_t idx = ((size_t)((t * 4 + j) * 16 + 4 * m + q) * 32 + l31) * 8 + 4 * lh;
            *(uint2*)(Hws + idx) = pk;
        }
    }
}

// ---------------- msg: We GEMM + contraction + sector-dense atomics ----------------
__global__ __launch_bounds__(256) void msg_kernel(const float* __restrict__ nf,
                                                  const int*   __restrict__ esrc,
                                                  const int*   __restrict__ edst,
                                                  const float* __restrict__ b2,
                                                  const short* __restrict__ W2k,
                                                  const short* __restrict__ Hws,
                                                  float* __restrict__ out) {
    __shared__ float msgbuf[32 * 8];           // [e][oo], oo = o - 8c
    const int tid = threadIdx.x;
    const int l31 = tid & 31;
    const int lh  = (tid >> 5) & 1;
    const int w   = tid >> 6;
    const int c   = blockIdx.x & 3;            // o-quad: o in [8c, 8c+8)
    const int s   = 4 * c + w;                 // slice: o in {2s, 2s+1}
    const int tg  = blockIdx.x >> 2;           // tile group 0..1023

    // W2 slice panel -> registers (64 arch VGPRs), once per block
    short8 Bf[2][8];
    #pragma unroll
    for (int n = 0; n < 2; ++n)
        #pragma unroll
        for (int ks = 0; ks < 8; ++ks)
            Bf[n][ks] = *(const short8*)(W2k + ((s * 16 + ks * 2 + lh) * 64 + n * 32 + l31) * 8);
    const float b2v0 = b2[l31 * 32 + 2 * s];
    const float b2v1 = b2[l31 * 32 + 2 * s + 1];

    for (int t = tg; t < B_TILES; t += 1024) {
        const int ebase = t * 32;
        const int srcv = esrc[ebase + l31];    // lanes 0..31 hold e0..e31

        // K-loop: A-frags from Hws (coalesced dwordx4), B in regs
        f32x16 acc[2];
        #pragma unroll
        for (int r = 0; r < 16; ++r) { acc[0][r] = b2v0; acc[1][r] = b2v1; }
        #pragma unroll
        for (int ks = 0; ks < 8; ++ks) {
            short8 a = *(const short8*)(Hws + ((size_t)(t * 16 + ks * 2 + lh) * 32 + l31) * 8);
            acc[0] = __builtin_amdgcn_mfma_f32_32x32x16_bf16(a, Bf[0][ks], acc[0], 0, 0, 0);
            acc[1] = __builtin_amdgcn_mfma_f32_32x32x16_bf16(a, Bf[1][ks], acc[1], 0, 0, 0);
        }

        // contraction over i = l31; DPP reduce; lanes 31/63 stash to msgbuf
        #pragma unroll
        for (int r = 0; r < 16; ++r) {
            int e  = (r & 3) + 8 * (r >> 2) + 4 * lh;          // 0..31
            int sv = __shfl(srcv, e);
            float x = nf[(size_t)sv * 32 + l31];               // 2 rows / instr, coalesced
            float v0 = x * acc[0][r];
            float v1 = x * acc[1][r];
            DPP_ADD(v0, 0x111); DPP_ADD(v1, 0x111);            // row_shr:1
            DPP_ADD(v0, 0x112); DPP_ADD(v1, 0x112);            // row_shr:2
            DPP_ADD(v0, 0x114); DPP_ADD(v1, 0x114);            // row_shr:4
            DPP_ADD(v0, 0x118); DPP_ADD(v1, 0x118);            // row_shr:8
            DPP_ADD(v0, 0x142); DPP_ADD(v1, 0x142);            // row_bcast15 -> lane31/63
            if (l31 == 31) {
                float2 pk = make_float2(v0, v1);
                *(float2*)(msgbuf + e * 8 + 2 * w) = pk;       // ds_write_b64, 2 lanes
            }
        }
        __syncthreads();                       // msgbuf complete (all 4 waves)

        // sector-dense scatter: 8 consecutive threads = 8 consecutive o of one edge
        {
            int e  = tid >> 3, oo = tid & 7;
            float v = msgbuf[e * 8 + oo];
            int dv = edst[ebase + e];          // broadcast within 8-thread group
            atomicAdd(out + (size_t)dv * 32 + 8 * c + oo, v);
        }
        __syncthreads();                       // protect msgbuf reuse next tile
    }
}

extern "C" void kernel_launch(void* const* d_in, const int* in_sizes, int n_in,
                              void* d_out, int out_size, void* d_ws, size_t ws_size,
                              hipStream_t stream) {
    const float* nf   = (const float*)d_in[0];
    const float* ef   = (const float*)d_in[1];
    const int*   src  = (const int*)  d_in[2];
    const int*   dst  = (const int*)  d_in[3];
    const float* W1   = (const float*)d_in[4];
    const float* b1   = (const float*)d_in[5];
    const float* W2   = (const float*)d_in[6];
    const float* b2   = (const float*)d_in[7];
    const float* bias = (const float*)d_in[8];
    float* out = (float*)d_out;
    short* W2k = (short*)d_ws;                 // 262144 B
    short* Hws = W2k + HWS_OFF;                // 51.2 MB bf16 H, A-frag layout

    prep_kernel<<<OUT_BLKS + W2K_BLKS + A_TILES, 256, 0, stream>>>(
        ef, W1, b1, W2, bias, out, W2k, Hws);
    msg_kernel<<<4096, 256, 0, stream>>>(nf, src, dst, b2, W2k, Hws, out);
}